// Round 2
// 1372.950 us; speedup vs baseline: 1.0385x; 1.0385x over previous
//
#include <hip/hip_runtime.h>

#define EPS 1e-5f

__device__ __forceinline__ float fast_rcp(float x) { return __builtin_amdgcn_rcpf(x); }
__device__ __forceinline__ float sigm(float x) { return fast_rcp(1.f + __expf(-x)); }
__device__ __forceinline__ float tanh_fast(float x) { return 1.f - 2.f * fast_rcp(1.f + __expf(2.f * x)); }
__device__ __forceinline__ float rdlane(float v, int l) {
    return __int_as_float(__builtin_amdgcn_readlane(__float_as_int(v), l));
}

// ---------------------------------------------------------------------------
// Kernel AB: one image per block (2048 blocks, 256 threads). (unchanged)
// ---------------------------------------------------------------------------
__global__ __launch_bounds__(256, 4) void kAB(
    const float* __restrict__ x,
    const float* __restrict__ w1, const float* __restrict__ cb1,
    const float* __restrict__ g1, const float* __restrict__ b1,
    const float* __restrict__ m1, const float* __restrict__ v1,
    const float* __restrict__ w2, const float* __restrict__ cb2,
    const float* __restrict__ g2, const float* __restrict__ b2,
    const float* __restrict__ m2, const float* __restrict__ v2,
    float* __restrict__ c)
{
    __shared__ float sc[16], sh[16];
    __shared__ float convbuf[6][36][17];   // conv rows for one strip, pad 17
    __shared__ float plds[16][12][13];     // pooled stage-A out, pad 13

    const int tid = threadIdx.x;
    const int img = blockIdx.x;
    const float* xb = x + (size_t)img * 62208;  // 3*144*144

    if (tid < 16) {
        float s = g1[tid] * rsqrtf(v1[tid] + EPS);
        sc[tid] = s;
        sh[tid] = b1[tid] + (cb1[tid] - m1[tid]) * s;
    }
    __syncthreads();

    for (int pp = 0; pp < 6; ++pp) {   // 6 strips of 6 conv rows (=2 pool rows)
        if (tid < 216) {
            const int ox = tid % 36;
            const int ry = tid / 36;                  // 0..5
            const int oy = pp * 6 + ry;
            const float* pbase = xb + oy * 576 + ox * 4;
            float4 patch[12];
#pragma unroll
            for (int ci = 0; ci < 3; ++ci)
#pragma unroll
                for (int dy = 0; dy < 4; ++dy)
                    patch[ci * 4 + dy] = *(const float4*)(pbase + ci * 20736 + dy * 144);
            float acc[16];
#pragma unroll
            for (int co = 0; co < 16; ++co) acc[co] = 0.f;
#pragma unroll
            for (int q = 0; q < 12; ++q) {
                const float4 pq = patch[q];
#pragma unroll
                for (int co = 0; co < 16; ++co) {
                    const float* wp = w1 + co * 48 + q * 4;   // uniform -> s_load
                    acc[co] = fmaf(pq.x, wp[0],
                              fmaf(pq.y, wp[1],
                              fmaf(pq.z, wp[2],
                              fmaf(pq.w, wp[3], acc[co]))));
                }
            }
#pragma unroll
            for (int co = 0; co < 16; ++co)
                convbuf[ry][ox][co] = fmaxf(fmaf(acc[co], sc[co], sh[co]), 0.f);
        }
        __syncthreads();
        // pool 3x3: items (pr in 2, px in 12, co in 16) = 384
        for (int i = tid; i < 384; i += 256) {
            const int pr = i & 1;
            const int px = (i >> 1) % 12;
            const int co = i / 24;
            float best = 0.f;
#pragma unroll
            for (int dy = 0; dy < 3; ++dy)
#pragma unroll
                for (int dx = 0; dx < 3; ++dx)
                    best = fmaxf(best, convbuf[pr * 3 + dy][px * 3 + dx][co]);
            plds[co][pp * 2 + pr][px] = best;
        }
        __syncthreads();
    }

    // Stage B on wave 0: conv2 over plds. lane = (ch, dy)
    if (tid < 64) {
        const int ch = tid >> 2, dy = tid & 3;
        const float4 wv = *(const float4*)(w2 + ch * 16 + dy * 4);
        const float scale = g2[0] * rsqrtf(v2[0] + EPS);
        const float shift = b2[0] + (cb2[0] - m2[0]) * scale;
        float best = 0.f;
#pragma unroll
        for (int oy = 0; oy < 3; ++oy)
#pragma unroll
            for (int ox = 0; ox < 3; ++ox) {
                const float* ab = &plds[ch][4 * oy + dy][4 * ox];
                float s = ab[0] * wv.x + ab[1] * wv.y + ab[2] * wv.z + ab[3] * wv.w;
#pragma unroll
                for (int off = 32; off >= 1; off >>= 1) s += __shfl_xor(s, off);
                float val = fmaxf(fmaf(s, scale, shift), 0.f);
                best = fmaxf(best, val);
            }
        if (tid == 0) c[img] = best;
    }
}

// ---------------------------------------------------------------------------
// Kernel C: gating MLP + argmax -> expert index p[32]. (unchanged)
// ---------------------------------------------------------------------------
__global__ __launch_bounds__(64) void kC(
    const float* __restrict__ c,
    const float* __restrict__ w1, const float* __restrict__ b1,
    const float* __restrict__ w2, const float* __restrict__ b2,
    const float* __restrict__ w3, const float* __restrict__ b3,
    int* __restrict__ p)
{
    const int b = threadIdx.x;
    if (b >= 32) return;
    const float* cb = c + b * 64;
    float h1[32];
#pragma unroll
    for (int j = 0; j < 32; ++j) {
        float s = b1[j];
        for (int i = 0; i < 64; ++i) s = fmaf(w1[j * 64 + i], cb[i], s);
        h1[j] = tanhf(s);
    }
    float h2[32];
#pragma unroll
    for (int j = 0; j < 32; ++j) {
        float s = b2[j];
#pragma unroll
        for (int i = 0; i < 32; ++i) s = fmaf(w2[j * 32 + i], h1[i], s);
        h2[j] = tanhf(s);
    }
    float best = -3.4e38f;
    int bi = 0;
#pragma unroll
    for (int j = 0; j < 6; ++j) {
        float s = b3[j];
#pragma unroll
        for (int i = 0; i < 32; ++i) s = fmaf(w3[j * 32 + i], h2[i], s);
        if (s > best) { best = s; bi = j; }  // strict > == first-max (jnp.argmax)
    }
    p[b] = bi;
}

// ---------------------------------------------------------------------------
// Kernel D: per-expert LSTM chain, 6 blocks x 1 wave.
// GATE-SPLIT LAYOUT: low half (lanes 0-31) owns gate rows I,F for hidden
// unit k; high half owns rows G,O.  Each lane does 64 fmas/step (was 128,
// duplicated across halves).  The 32 readlane(h,j) broadcasts are SGPRs
// shared by both halves; only the per-lane weight VGPR differs.
// Weights held in 16 NAMED float4s (scalar member access only) -> SROA
// promotion (previous array form stayed in memory: VGPR=80 < the 128 regs
// the arrays needed).  Activation unified bitwise:
//   act = fma(C2, rcp(1+exp(C3*x)), C1)  ==  sigm (low) / tanh_fast (high)
// (fma(1,r,0)=r; fma(-2,r,1)=1-2r exactly since 2r is exact).
// One shfl_xor(32) pair exchanges (i,f)<->(g,o); both halves then hold
// identical valid (cc,h) so the h broadcasts stay correct.
// rvec capture: v_cmp+cndmask select (writelane builtin not available).
// ---------------------------------------------------------------------------
__global__ __launch_bounds__(64, 1) void kD(
    const float* __restrict__ c, const int* __restrict__ p,
    const float* __restrict__ wih, const float* __restrict__ whh,
    const float* __restrict__ bih, const float* __restrict__ bhh,
    const float* __restrict__ hn0,
    const float* __restrict__ ow, const float* __restrict__ obias,
    float* __restrict__ out)
{
    const int e = blockIdx.x;
    const int lane = threadIdx.x;   // 0..63
    const int k = lane & 31;
    const int hf = lane >> 5;       // 0: rows I,F   1: rows G,O
    const int rowA = k + (hf << 6);        // I (0-31)  or G (64-95)
    const int rowB = rowA + 32;            // F (32-63) or O (96-127)

    const float* wa = whh + e * 4096 + rowA * 32;
    const float* wb = whh + e * 4096 + rowB * 32;
    const float4 a0 = *(const float4*)(wa +  0), a1 = *(const float4*)(wa +  4);
    const float4 a2 = *(const float4*)(wa +  8), a3 = *(const float4*)(wa + 12);
    const float4 a4 = *(const float4*)(wa + 16), a5 = *(const float4*)(wa + 20);
    const float4 a6 = *(const float4*)(wa + 24), a7 = *(const float4*)(wa + 28);
    const float4 b0 = *(const float4*)(wb +  0), b1 = *(const float4*)(wb +  4);
    const float4 b2 = *(const float4*)(wb +  8), b3 = *(const float4*)(wb + 12);
    const float4 b4 = *(const float4*)(wb + 16), b5 = *(const float4*)(wb + 20);
    const float4 b6 = *(const float4*)(wb + 24), b7 = *(const float4*)(wb + 28);

    const float wiA = wih[e * 128 + rowA], wiB = wih[e * 128 + rowB];
    const float bA  = bih[e * 128 + rowA] + bhh[e * 128 + rowA];
    const float bB  = bih[e * 128 + rowB] + bhh[e * 128 + rowB];

    // unified activation constants: low = sigm, high = tanh_fast (bitwise)
    const float C1 = hf ? 1.f : 0.f;
    const float C2 = hf ? -2.f : 1.f;
    const float C3 = hf ? 2.f : -1.f;

    float h = hn0[e * 32 + k];   // chain state (replicated in both halves)

    for (int b = 0; b < 32; ++b) {
        if (p[b] != e) continue;  // wave-uniform
        const float cvec = c[b * 64 + lane];
        float cc = 0.f;
        float rvec = 0.f;         // lane t holds r_t = h_t[31]
        for (int t = 0; t < 64; ++t) {
            const float xt = rdlane(cvec, t);
            float A0 = fmaf(wiA, xt, bA), A1 = 0.f;
            float B0 = fmaf(wiB, xt, bB), B1 = 0.f;
#define GRP(q, av, bv) { \
            const float h0 = rdlane(h, 4*q + 0); \
            const float h1 = rdlane(h, 4*q + 1); \
            const float h2 = rdlane(h, 4*q + 2); \
            const float h3 = rdlane(h, 4*q + 3); \
            A0 = fmaf(av.x, h0, A0); A1 = fmaf(av.y, h1, A1); \
            A0 = fmaf(av.z, h2, A0); A1 = fmaf(av.w, h3, A1); \
            B0 = fmaf(bv.x, h0, B0); B1 = fmaf(bv.y, h1, B1); \
            B0 = fmaf(bv.z, h2, B0); B1 = fmaf(bv.w, h3, B1); }
            GRP(0, a0, b0) GRP(1, a1, b1) GRP(2, a2, b2) GRP(3, a3, b3)
            GRP(4, a4, b4) GRP(5, a5, b5) GRP(6, a6, b6) GRP(7, a7, b7)
#undef GRP
            const float accA = A0 + A1;   // i (low) / g (high)
            const float accB = B0 + B1;   // f (low) / o (high)
            const float actA = fmaf(C2, fast_rcp(1.f + __expf(C3 * accA)), C1);
            const float actB = fast_rcp(1.f + __expf(-accB));
            const float xA = __shfl_xor(actA, 32);   // cross-half partner
            const float xB = __shfl_xor(actB, 32);
            const float ig = hf ? xA   : actA;
            const float fg = hf ? xB   : actB;
            const float gg = hf ? actA : xA;
            const float og = hf ? actB : xB;
            cc = fmaf(fg, cc, ig * gg);
            h = og * tanh_fast(cc);       // identical in both halves
            const float h31 = rdlane(h, 31);
            rvec = (lane == t) ? h31 : rvec;
        }
#pragma unroll
        for (int a = 0; a < 6; ++a) {
            float tsum = rvec * ow[a * 64 + lane];
#pragma unroll
            for (int off = 32; off >= 1; off >>= 1) tsum += __shfl_xor(tsum, off);
            if (lane == 0) out[b * 6 + a] = tsum + obias[a];
        }
    }
}

extern "C" void kernel_launch(void* const* d_in, const int* in_sizes, int n_in,
                              void* d_out, int out_size, void* d_ws, size_t ws_size,
                              hipStream_t stream)
{
    const float* x    = (const float*)d_in[0];
    const float* c1w  = (const float*)d_in[1];
    const float* c1b  = (const float*)d_in[2];
    const float* bn1g = (const float*)d_in[3];
    const float* bn1b = (const float*)d_in[4];
    const float* bn1m = (const float*)d_in[5];
    const float* bn1v = (const float*)d_in[6];
    const float* c2w  = (const float*)d_in[7];
    const float* c2b  = (const float*)d_in[8];
    const float* bn2g = (const float*)d_in[9];
    const float* bn2b = (const float*)d_in[10];
    const float* bn2m = (const float*)d_in[11];
    const float* bn2v = (const float*)d_in[12];
    const float* pw1  = (const float*)d_in[13];
    const float* pb1  = (const float*)d_in[14];
    const float* pw2  = (const float*)d_in[15];
    const float* pb2  = (const float*)d_in[16];
    const float* pw3  = (const float*)d_in[17];
    const float* pb3  = (const float*)d_in[18];
    const float* wih  = (const float*)d_in[19];
    const float* whh  = (const float*)d_in[20];
    const float* bihp = (const float*)d_in[21];
    const float* bhhp = (const float*)d_in[22];
    const float* hn0  = (const float*)d_in[23];
    const float* ow   = (const float*)d_in[24];
    const float* ob   = (const float*)d_in[25];
    float* out = (float*)d_out;

    float* c = (float*)d_ws;                                  // 2048 floats
    int*   p = (int*)((char*)d_ws + 2048 * sizeof(float));    // 32 ints

    kAB<<<2048, 256, 0, stream>>>(x, c1w, c1b, bn1g, bn1b, bn1m, bn1v,
                                  c2w, c2b, bn2g, bn2b, bn2m, bn2v, c);
    kC<<<1, 64, 0, stream>>>(c, pw1, pb1, pw2, pb2, pw3, pb3, p);
    kD<<<6, 64, 0, stream>>>(c, p, wih, whh, bihp, bhhp, hn0, ow, ob, out);
}